// Round 2
// baseline (483.719 us; speedup 1.0000x reference)
//
#include <hip/hip_runtime.h>
#include <hip/hip_fp16.h>

// FeatureSampler: BEVFormer-style multi-cam multi-level bilinear sampling.
// B=2, N=6 cams, C=256 ch, M=900 queries, 4 levels (fp32 in, fp32 out).
//
// Round 1 analysis: original gather layout (BN,C,H,W) forces stride-H*W
// channel gathers -> 64B line per 4B used (16x over-fetch), ~2.5-3 GB HBM
// traffic, 390 us HBM-bound. Fix: transpose features to (BN,H,W,C) in d_ws
// as fp16 (halves write + sampler read; error ~5e-3 << 2.5e-2 threshold),
// then every bilinear corner is a contiguous 512B channel read.

static constexpr float EPSV = 1e-5f;
static constexpr int Bn = 2, Nn = 6, Cn = 256, Mn = 900;

// Level geometry
static constexpr int H0=116, W0=200, HW0=H0*W0;   // 23200
static constexpr int H1= 58, W1=100, HW1=H1*W1;   // 5800
static constexpr int H2= 29, W2= 50, HW2=H2*W2;   // 1450
static constexpr int H3= 15, W3= 25, HW3=H3*W3;   // 375

// fp16 transposed-buffer offsets (in elements) inside d_ws
static constexpr size_t OFF0 = 0;
static constexpr size_t OFF1 = OFF0 + (size_t)Bn*Nn*HW0*Cn;  // 71,270,400
static constexpr size_t OFF2 = OFF1 + (size_t)Bn*Nn*HW1*Cn;  // 89,088,000
static constexpr size_t OFF3 = OFF2 + (size_t)Bn*Nn*HW2*Cn;  // 93,542,400
// total 94,694,400 halves = 189.4 MB < ws (~1.1 GB)

struct alignas(8) Half4 { __half2 a, b; };

// Transpose (BN,C,HW) fp32 -> (BN,HW,C) fp16, 64x64 LDS tiles.
// VEC=true: float4 global reads (HW divisible by 4 required; levels 0,1).
template<bool VEC>
__global__ __launch_bounds__(256) void transpose_kernel(
    const float* __restrict__ in, __half* __restrict__ outT, int HW)
{
    __shared__ float tile[64][68];   // pad 68: 2-way max on stores (free)
    const int t   = threadIdx.x;
    const int hw0 = blockIdx.x * 64;
    const int c0  = blockIdx.y * 64;
    const int bn  = blockIdx.z;
    const float* src = in + ((size_t)bn * Cn + c0) * HW;

    if (VEC) {
        const int hwi = (t & 15) * 4;    // 0..60, contiguous across 16 lanes
        const int cr  = t >> 4;          // 0..15
#pragma unroll
        for (int i = 0; i < 4; ++i) {
            const int c = cr + i * 16;   // 0..63
            if (hw0 + hwi < HW) {        // HW%4==0 -> whole float4 valid
                const float4 v = *(const float4*)(src + (size_t)c * HW + hw0 + hwi);
                *(float4*)&tile[c][hwi] = v;
            }
        }
    } else {
        const int lane = t & 63;         // hw within tile, coalesced
        const int cr   = t >> 6;         // 0..3
#pragma unroll
        for (int i = 0; i < 16; ++i) {
            const int c = cr + i * 4;    // 0..63
            if (hw0 + lane < HW)
                tile[c][lane] = src[(size_t)c * HW + hw0 + lane];
        }
    }
    __syncthreads();

    // Write out: lanes contiguous along C (16 lanes x 4ch = 64 ch), fp16.
    const int cq = (t & 15) * 4;
    const int r0 = t >> 4;               // 0..15
#pragma unroll
    for (int i = 0; i < 4; ++i) {
        const int row = r0 + i * 16;     // hw within tile
        if (hw0 + row < HW) {
            Half4 h;
            h.a = __floats2half2_rn(tile[cq+0][row], tile[cq+1][row]);
            h.b = __floats2half2_rn(tile[cq+2][row], tile[cq+3][row]);
            *(Half4*)(outT + ((size_t)bn * HW + hw0 + row) * Cn + c0 + cq) = h;
        }
    }
}

// Sampler: one wave per (b,m) query per y-slice; lane = channel pair.
// Projection math: reference's gx=(px/W)*2-1 then grid_sample's
// x=(gx+1)*W/2-0.5 collapses to x=px-0.5 for every level.
__global__ __launch_bounds__(256) void FeatureSampler_74062416052404_kernel(
    const __half* __restrict__ ws,
    const float* __restrict__ refp, const float* __restrict__ l2i,
    float* __restrict__ out)
{
    const int q = blockIdx.x * 2 + threadIdx.y;   // 0..1799
    const int b = q / Mn;
    const int m = q - b * Mn;
    const int c = threadIdx.x * 2;                // channel pair base

    const float rx = refp[q * 3 + 0] * 122.4f - 61.2f;
    const float ry = refp[q * 3 + 1] * 122.4f - 61.2f;
    const float rz = refp[q * 3 + 2] * 20.0f  - 10.0f;

    const __half* T[4] = { ws + OFF0, ws + OFF1, ws + OFF2, ws + OFF3 };
    constexpr int Hs[4] = {H0, H1, H2, H3};
    constexpr int Ws_[4] = {W0, W1, W2, W3};

    float ax = 0.0f, ay = 0.0f;   // channel-pair accumulators
    float wsum = 0.0f;

    for (int n = 0; n < Nn; ++n) {
        const float* L = l2i + (size_t)(b * Nn + n) * 16;
        const float cx = L[0] * rx + L[1] * ry + L[2]  * rz + L[3];
        const float cy = L[4] * rx + L[5] * ry + L[6]  * rz + L[7];
        const float cz = L[8] * rx + L[9] * ry + L[10] * rz + L[11];
        if (!(cz > EPSV)) continue;    // wave-uniform skip
        wsum += 1.0f;

        const float inv = 1.0f / (cz + EPSV);
        const float x = cx * inv - 0.5f;
        const float y = cy * inv - 0.5f;
        const float x0f = floorf(x), y0f = floorf(y);
        const float wx1 = x - x0f, wx0 = 1.0f - wx1;
        const float wy1 = y - y0f, wy0 = 1.0f - wy1;

#pragma unroll
        for (int l = 0; l < 4; ++l) {
            const int H = Hs[l], W = Ws_[l];
            const bool vx0 = (x0f >= 0.0f) & (x0f < (float)W);
            const bool vx1 = (x0f >= -1.0f) & (x0f < (float)(W - 1));
            const bool vy0 = (y0f >= 0.0f) & (y0f < (float)H);
            const bool vy1 = (y0f >= -1.0f) & (y0f < (float)(H - 1));
            if (!((vx0 | vx1) & (vy0 | vy1))) continue;   // wave-uniform

            const int xi0 = (int)x0f;
            const int yi0 = (int)y0f;
            // pixel base in transposed (BN,HW,C) fp16 buffer
            const __half* base = T[l]
                + ((size_t)((b * Nn + n) * (size_t)(H * W)) + (size_t)yi0 * W + xi0) * Cn + c;

            float sx = 0.0f, sy = 0.0f;
            if (vx0 & vy0) {
                const float2 v = __half22float2(*(const __half2*)(base));
                sx += wx0 * wy0 * v.x;  sy += wx0 * wy0 * v.y;
            }
            if (vx1 & vy0) {
                const float2 v = __half22float2(*(const __half2*)(base + Cn));
                sx += wx1 * wy0 * v.x;  sy += wx1 * wy0 * v.y;
            }
            if (vx0 & vy1) {
                const float2 v = __half22float2(*(const __half2*)(base + (size_t)W * Cn));
                sx += wx0 * wy1 * v.x;  sy += wx0 * wy1 * v.y;
            }
            if (vx1 & vy1) {
                const float2 v = __half22float2(*(const __half2*)(base + (size_t)W * Cn + Cn));
                sx += wx1 * wy1 * v.x;  sy += wx1 * wy1 * v.y;
            }
            ax += sx;  ay += sy;
        }
    }

    const float scale = 0.25f / (wsum + EPSV);
    float2 r;  r.x = ax * scale;  r.y = ay * scale;
    *(float2*)(out + (size_t)q * Cn + c) = r;
}

extern "C" void kernel_launch(void* const* d_in, const int* in_sizes, int n_in,
                              void* d_out, int out_size, void* d_ws, size_t ws_size,
                              hipStream_t stream) {
    const float* f0   = (const float*)d_in[0];
    const float* f1   = (const float*)d_in[1];
    const float* f2   = (const float*)d_in[2];
    const float* f3   = (const float*)d_in[3];
    const float* refp = (const float*)d_in[4];
    const float* l2i  = (const float*)d_in[5];
    float* out = (float*)d_out;
    __half* ws = (__half*)d_ws;

    // Transpose each level: grid (hw_tiles, c_tiles=4, BN=12)
    transpose_kernel<true ><<<dim3((HW0 + 63) / 64, 4, Bn * Nn), 256, 0, stream>>>(f0, ws + OFF0, HW0);
    transpose_kernel<true ><<<dim3((HW1 + 63) / 64, 4, Bn * Nn), 256, 0, stream>>>(f1, ws + OFF1, HW1);
    transpose_kernel<false><<<dim3((HW2 + 63) / 64, 4, Bn * Nn), 256, 0, stream>>>(f2, ws + OFF2, HW2);
    transpose_kernel<false><<<dim3((HW3 + 63) / 64, 4, Bn * Nn), 256, 0, stream>>>(f3, ws + OFF3, HW3);

    // Sample: 2 queries per block (one per 128-thread y-slice), lane = ch pair
    FeatureSampler_74062416052404_kernel<<<dim3(Bn * Mn / 2), dim3(128, 2), 0, stream>>>(
        ws, refp, l2i, out);
}

// Round 3
// 473.949 us; speedup vs baseline: 1.0206x; 1.0206x over previous
//
#include <hip/hip_runtime.h>
#include <hip/hip_fp16.h>

// FeatureSampler: BEVFormer-style multi-cam multi-level bilinear sampling.
// B=2, N=6 cams, C=256 ch, M=900 queries, 4 levels (fp32 in, fp32 out).
//
// R1: direct gather in (BN,C,H,W): stride-HW channel gathers fetch a 64B line
//     per 4B used -> ~2.4 GB HBM, 390 us.
// R2: fp16 channel-last transpose + gather: 484 us (REGRESSION, no per-kernel
//     visibility). Suspects: LDS 8-way read conflict in transpose (pad 68:
//     68*4=16 mod 32 -> 2 banks/quarter-wave), and sampler's 24 branch-split
//     latency rounds.
// R3: (a) single fused transpose dispatch, tile pad 65 (65*4=4 mod 32 -> 2-way
//     = free both directions); (b) sampler: clamped-index + zero-weight corners
//     (4 loads issue together per level), level validity nests (same px,py;
//     W,H shrink) -> break; (c) only 2 dispatches so both show in rocprof.

static constexpr float EPSV = 1e-5f;
static constexpr int Bn = 2, Nn = 6, Cn = 256, Mn = 900;

static constexpr int Hs[4] = {116, 58, 29, 15};
static constexpr int Wd[4] = {200, 100, 50, 25};
static constexpr int HWs[4] = {23200, 5800, 1450, 375};
// fp16 channel-last buffer offsets in d_ws (elements)
static constexpr size_t OFFe[4] = {0, 71270400, 89088000, 93542400};
// total 94,694,400 halves = 189.4 MB << ws (~1.1 GB)

// hw-tiles per level (ceil(HW/64)) and cumulative
static constexpr int CUM0 = 363, CUM1 = 363 + 91, CUM2 = CUM1 + 23, CUM3 = CUM2 + 6; // 483

struct alignas(8) Half4 { __half2 a, b; };

// Fused transpose: (BN,C,HW) fp32 -> (BN,HW,C) fp16 for all 4 levels.
// grid = (483 hw-tiles, 4 c-tiles, 12 bn), block = 256.
__global__ __launch_bounds__(256) void transpose_all(
    const float* __restrict__ f0, const float* __restrict__ f1,
    const float* __restrict__ f2, const float* __restrict__ f3,
    __half* __restrict__ ws)
{
    __shared__ float tile[64][65];   // 65*4 = 260 = 4 mod 32 -> 2-way reads (free)

    const int tb = blockIdx.x;
    int l, t0;
    const float* src;
    if (tb < CUM0)      { l = 0; t0 = 0;    src = f0; }
    else if (tb < CUM1) { l = 1; t0 = CUM0; src = f1; }
    else if (tb < CUM2) { l = 2; t0 = CUM1; src = f2; }
    else                { l = 3; t0 = CUM2; src = f3; }
    const int HW  = HWs[l];
    const int hw0 = (tb - t0) * 64;
    const int c0  = blockIdx.y * 64;
    const int bn  = blockIdx.z;
    const float* in = src + ((size_t)bn * Cn + c0) * HW;

    const int t    = threadIdx.x;
    const int lane = t & 63;        // hw within tile -> coalesced 256B per inst
    const int cw   = (t >> 6) * 16; // wave w covers c rows 16w..16w+15
    const bool inb = (hw0 + lane) < HW;
#pragma unroll
    for (int i = 0; i < 16; ++i) {
        const int c = cw + i;
        if (inb) tile[c][lane] = in[(size_t)c * HW + hw0 + lane];
    }
    __syncthreads();

    // write: 16 lanes x 4ch(fp16) = 128B contiguous segments
    const int cq = (t & 15) * 4;
    const int r0 = t >> 4;
    __half* outT = ws + OFFe[l];
#pragma unroll
    for (int i = 0; i < 4; ++i) {
        const int row = r0 + i * 16;
        if (hw0 + row < HW) {
            Half4 h;
            h.a = __floats2half2_rn(tile[cq + 0][row], tile[cq + 1][row]);
            h.b = __floats2half2_rn(tile[cq + 2][row], tile[cq + 3][row]);
            *(Half4*)(outT + ((size_t)bn * HW + hw0 + row) * Cn + c0 + cq) = h;
        }
    }
}

// Sampler: 2 queries per 256-thread block; 128 threads (2 waves) per query,
// lane = channel pair (half2 = 4B -> 256B coalesced per corner per wave).
__global__ __launch_bounds__(256) void FeatureSampler_74062416052404_kernel(
    const __half* __restrict__ ws,
    const float* __restrict__ refp, const float* __restrict__ l2i,
    float* __restrict__ out)
{
    const int q = blockIdx.x * 2 + threadIdx.y;   // 0..1799
    const int b = q / Mn;
    const int c = threadIdx.x * 2;                // channel pair base

    const float rx = refp[q * 3 + 0] * 122.4f - 61.2f;
    const float ry = refp[q * 3 + 1] * 122.4f - 61.2f;
    const float rz = refp[q * 3 + 2] * 20.0f  - 10.0f;

    float ax = 0.0f, ay = 0.0f;
    float wsum = 0.0f;

    for (int n = 0; n < Nn; ++n) {
        const float* L = l2i + (size_t)(b * Nn + n) * 16;
        const float cx = L[0] * rx + L[1] * ry + L[2]  * rz + L[3];
        const float cy = L[4] * rx + L[5] * ry + L[6]  * rz + L[7];
        const float cz = L[8] * rx + L[9] * ry + L[10] * rz + L[11];
        if (!(cz > EPSV)) continue;               // wave-uniform
        wsum += 1.0f;

        const float inv = 1.0f / (cz + EPSV);
        const float x = cx * inv - 0.5f;
        const float y = cy * inv - 0.5f;
        const float x0f = floorf(x), y0f = floorf(y);
        const float wx1 = x - x0f, wx0 = 1.0f - wx1;
        const float wy1 = y - y0f, wy0 = 1.0f - wy1;
        const int xi0 = (int)x0f;                 // exact: x0f integral, |.|<2^31 when valid
        const int yi0 = (int)y0f;

#pragma unroll
        for (int l = 0; l < 4; ++l) {
            const int W = Wd[l], H = Hs[l];
            // some-corner-valid region [-1,W)x[-1,H) shrinks with l -> break
            const bool any = (x0f >= -1.0f) & (x0f < (float)W) &
                             (y0f >= -1.0f) & (y0f < (float)H);
            if (!any) break;                      // wave-uniform

            // per-corner masked weights + clamped indices (branch-free corners)
            const float a0 = (x0f >= 0.0f)           ? wx0 : 0.0f;
            const float a1 = (x0f < (float)(W - 1))  ? wx1 : 0.0f;
            const float b0 = (y0f >= 0.0f)           ? wy0 : 0.0f;
            const float b1 = (y0f < (float)(H - 1))  ? wy1 : 0.0f;
            const int x0c = max(xi0, 0), x1c = min(xi0 + 1, W - 1);
            const int y0c = max(yi0, 0), y1c = min(yi0 + 1, H - 1);

            const __half* base = ws + OFFe[l]
                + ((size_t)(b * Nn + n) * (size_t)(H * W)) * Cn + c;
            // all 4 loads issue back-to-back (no branches between them)
            const __half2 v00 = *(const __half2*)(base + (size_t)(y0c * W + x0c) * Cn);
            const __half2 v01 = *(const __half2*)(base + (size_t)(y0c * W + x1c) * Cn);
            const __half2 v10 = *(const __half2*)(base + (size_t)(y1c * W + x0c) * Cn);
            const __half2 v11 = *(const __half2*)(base + (size_t)(y1c * W + x1c) * Cn);

            const float w00 = a0 * b0, w01 = a1 * b0, w10 = a0 * b1, w11 = a1 * b1;
            const float2 f00 = __half22float2(v00), f01 = __half22float2(v01);
            const float2 f10 = __half22float2(v10), f11 = __half22float2(v11);
            ax += w00 * f00.x + w01 * f01.x + w10 * f10.x + w11 * f11.x;
            ay += w00 * f00.y + w01 * f01.y + w10 * f10.y + w11 * f11.y;
        }
    }

    const float scale = 0.25f / (wsum + EPSV);
    float2 r;  r.x = ax * scale;  r.y = ay * scale;
    *(float2*)(out + (size_t)q * Cn + c) = r;
}

extern "C" void kernel_launch(void* const* d_in, const int* in_sizes, int n_in,
                              void* d_out, int out_size, void* d_ws, size_t ws_size,
                              hipStream_t stream) {
    const float* f0   = (const float*)d_in[0];
    const float* f1   = (const float*)d_in[1];
    const float* f2   = (const float*)d_in[2];
    const float* f3   = (const float*)d_in[3];
    const float* refp = (const float*)d_in[4];
    const float* l2i  = (const float*)d_in[5];
    float* out = (float*)d_out;
    __half* ws = (__half*)d_ws;

    transpose_all<<<dim3(CUM3, 4, Bn * Nn), 256, 0, stream>>>(f0, f1, f2, f3, ws);
    FeatureSampler_74062416052404_kernel<<<dim3(Bn * Mn / 2), dim3(128, 2), 0, stream>>>(
        ws, refp, l2i, out);
}

// Round 4
// 382.457 us; speedup vs baseline: 1.2648x; 1.2392x over previous
//
#include <hip/hip_runtime.h>

// FeatureSampler: BEVFormer-style multi-cam multi-level bilinear sampling.
// B=2, N=6 cams, C=256 ch, M=900 queries, 4 levels. fp32 in/out.
//
// R1 (direct branchy gather):       390 us
// R2 (fp16 transpose + gather):     484 us
// R3 (fused transpose, bank fix):   474 us
// Cross-round analysis: top-5 dispatches are always harness poison-fills
// (1.14 GB ws fill ~170 us) + input restores; our kernels never surface and a
// genuine LDS-conflict fix moved total only -10 us -> dur_us carries a large
// fixed harness component. The transpose (379 MB rd + 190 MB wr per call) is
// a net loss vs direct gather (~260 MB line-granular traffic, L2/LLC-assisted).
//
// R4: direct sampling, optimized:
//  - x0/x1 corners are adjacent in W -> ONE float2 load per corner-row
//    (2 loads/cam-level, issued back-to-back, branch-free) instead of 4
//    branch-separated scalar loads.
//  - pair base xp = clamp(xi0, 0, W-2); value swizzle (lo ? v.x : v.y)
//    handles xi0==-1 / xi0==W-1 without ever reading OOB.
//  - per-corner zero-masked weights; wave-uniform early break across the
//    nested level validity regions [-1,W)x[-1,H).

static constexpr float EPSV = 1e-5f;
static constexpr int Bn = 2, Nn = 6, Cn = 256, Mn = 900;

static constexpr int Hs[4]  = {116, 58, 29, 15};
static constexpr int Wd[4]  = {200, 100, 50, 25};
static constexpr int HWs[4] = {23200, 5800, 1450, 375};

__global__ __launch_bounds__(256) void FeatureSampler_74062416052404_kernel(
    const float* __restrict__ f0, const float* __restrict__ f1,
    const float* __restrict__ f2, const float* __restrict__ f3,
    const float* __restrict__ refp, const float* __restrict__ l2i,
    float* __restrict__ out)
{
    const int q = blockIdx.x;            // 0..1799, one query per block
    const int b = (q >= Mn) ? 1 : 0;
    const int c = threadIdx.x;           // channel

    const float rx = refp[q * 3 + 0] * 122.4f - 61.2f;
    const float ry = refp[q * 3 + 1] * 122.4f - 61.2f;
    const float rz = refp[q * 3 + 2] * 20.0f  - 10.0f;

    const float* const feats[4] = {f0, f1, f2, f3};
    // per-lane channel offsets per level (c * HW), computed once
    const int cHW0 = c * HWs[0], cHW1 = c * HWs[1], cHW2 = c * HWs[2], cHW3 = c * HWs[3];
    const int cHW[4] = {cHW0, cHW1, cHW2, cHW3};

    float acc  = 0.0f;
    float wsum = 0.0f;

    for (int n = 0; n < Nn; ++n) {
        const float* L = l2i + (size_t)(b * Nn + n) * 16;
        const float cx = L[0] * rx + L[1] * ry + L[2]  * rz + L[3];
        const float cy = L[4] * rx + L[5] * ry + L[6]  * rz + L[7];
        const float cz = L[8] * rx + L[9] * ry + L[10] * rz + L[11];
        if (!(cz > EPSV)) continue;      // wave-uniform skip, contributes 0/0
        wsum += 1.0f;

        const float inv = 1.0f / (cz + EPSV);
        const float x = cx * inv - 0.5f;  // same pixel coord for every level
        const float y = cy * inv - 0.5f;
        const float x0f = floorf(x), y0f = floorf(y);
        const float wx1 = x - x0f, wx0 = 1.0f - wx1;
        const float wy1 = y - y0f, wy0 = 1.0f - wy1;

#pragma unroll
        for (int l = 0; l < 4; ++l) {
            const int W = Wd[l], H = Hs[l];
            // any-corner-valid region [-1,W)x[-1,H) strictly nests as l grows
            const bool any = (x0f >= -1.0f) & (x0f < (float)W) &
                             (y0f >= -1.0f) & (y0f < (float)H);
            if (!any) break;             // wave-uniform

            const int xi0 = (int)x0f;    // exact int when in valid range
            const int yi0 = (int)y0f;

            // masked bilinear weights (corner invalid -> weight 0)
            const float a0 = (xi0 >= 0)     ? wx0 : 0.0f;
            const float a1 = (xi0 <  W - 1) ? wx1 : 0.0f;
            const float b0 = (yi0 >= 0)     ? wy0 : 0.0f;
            const float b1 = (yi0 <  H - 1) ? wy1 : 0.0f;

            // pair base: always reads a fully in-bounds float2 (x, x+1)
            const int xp  = min(max(xi0, 0), W - 2);
            const bool lo = (xi0 == xp);           // false only at edges
            const int y0c = max(yi0, 0);
            const int y1c = min(yi0 + 1, H - 1);

            const float* base = feats[l] + (size_t)(b * Nn + n) * (Cn * HWs[l]) + cHW[l];
            // two 8B loads, issued back-to-back, no branches between
            const float2 r0 = *(const float2*)(base + y0c * W + xp);
            const float2 r1 = *(const float2*)(base + y1c * W + xp);

            // swizzle for edge clamp: xi0==-1 -> x1 corner is r.x;
            // xi0==W-1 -> x0 corner is r.y (other weight is 0 in both cases)
            const float v00 = lo ? r0.x : r0.y;
            const float v01 = lo ? r0.y : r0.x;
            const float v10 = lo ? r1.x : r1.y;
            const float v11 = lo ? r1.y : r1.x;

            acc += (a0 * b0) * v00 + (a1 * b0) * v01
                 + (a0 * b1) * v10 + (a1 * b1) * v11;
        }
    }

    out[(size_t)q * Cn + c] = acc * 0.25f / (wsum + EPSV);
}

extern "C" void kernel_launch(void* const* d_in, const int* in_sizes, int n_in,
                              void* d_out, int out_size, void* d_ws, size_t ws_size,
                              hipStream_t stream) {
    const float* f0   = (const float*)d_in[0];
    const float* f1   = (const float*)d_in[1];
    const float* f2   = (const float*)d_in[2];
    const float* f3   = (const float*)d_in[3];
    const float* refp = (const float*)d_in[4];
    const float* l2i  = (const float*)d_in[5];
    float* out = (float*)d_out;

    FeatureSampler_74062416052404_kernel<<<dim3(Bn * Mn), dim3(256), 0, stream>>>(
        f0, f1, f2, f3, refp, l2i, out);
}